// Round 7
// baseline (33.064 us; speedup 1.0000x reference)
//
#include <hip/hip_runtime.h>
#include <math.h>

#define B_SZ 2
#define T_SZ 512
#define D_SZ 64
#define ELEMS 4096            // D*D

// chunked-scan geometry
#define CL   16               // timesteps per chunk
#define NK   32               // chunks per batch (NK*CL == T_SZ)
#define RCW  512              // rc elements per block window (8 windows)
#define NPW  8                // rc windows (NPW*RCW == ELEMS)

// ws layout (bytes)
#define DECAY_OFF 0
#define DECAY_BYTES ((size_t)B_SZ * D_SZ * T_SZ * 4)              // 262144
#define M_OFF   (DECAY_OFF + DECAY_BYTES)                          // 262144
#define M_BYTES ((size_t)B_SZ * T_SZ * 4)                          // 4096
#define R_OFF   (M_OFF + M_BYTES)
#define TAILS_OFF (R_OFF + M_BYTES)                                // 270336
#define TAILS_BYTES ((size_t)B_SZ * NK * ELEMS * 4)                // 1 MB
#define CIN_OFF  (TAILS_OFF + TAILS_BYTES)
#define WS_NEEDED (CIN_OFF + TAILS_BYTES)                          // ~2.26 MB

// fallback geometry (round-6 path)
#define NCH  32
#define CLEN 16
#define NCOL 16

// Kernel 1: per-(b,t) LayerNorm stats over D*D + row-dot with dt_w, softplus,
// decay = exp(softplus(dot+dt_b) * -exp(log_A[r])). Writes decay (transposed
// [b][r][t]) and stats SoA (M=mu*rs, R=rs).
__global__ __launch_bounds__(256) void ln_dt_kernel(
    const float* __restrict__ x, const float* __restrict__ log_A,
    const float* __restrict__ dt_w, const float* __restrict__ dt_b,
    const float* __restrict__ ln_w, const float* __restrict__ ln_b,
    float* __restrict__ decay_t, float* __restrict__ Mst, float* __restrict__ Rst)
{
    const int bt  = blockIdx.x;
    const int tid = threadIdx.x;
    const size_t base = (size_t)bt * ELEMS;

    float4 v[4];
    float sum = 0.f, sumsq = 0.f;
    const float4* xv4 = reinterpret_cast<const float4*>(x + base);
#pragma unroll
    for (int k = 0; k < 4; ++k) {
        v[k] = xv4[tid + 256 * k];
        sum   += v[k].x + v[k].y + v[k].z + v[k].w;
        sumsq += v[k].x * v[k].x + v[k].y * v[k].y + v[k].z * v[k].z + v[k].w * v[k].w;
    }

    __shared__ float red0[4], red1[4];
#pragma unroll
    for (int off = 32; off; off >>= 1) {
        sum   += __shfl_down(sum, off);
        sumsq += __shfl_down(sumsq, off);
    }
    const int wave = tid >> 6;
    if ((tid & 63) == 0) { red0[wave] = sum; red1[wave] = sumsq; }
    __syncthreads();
    sum   = red0[0] + red0[1] + red0[2] + red0[3];
    sumsq = red1[0] + red1[1] + red1[2] + red1[3];

    const float mu = sum * (1.f / ELEMS);
    const float var = sumsq * (1.f / ELEMS) - mu * mu;
    const float rs = rsqrtf(var + 1e-5f);

    const float4* w4p = reinterpret_cast<const float4*>(ln_w);
    const float4* b4p = reinterpret_cast<const float4*>(ln_b);
    const float4* dw4 = reinterpret_cast<const float4*>(dt_w);
    float dot[4] = {0.f, 0.f, 0.f, 0.f};
#pragma unroll
    for (int k = 0; k < 4; ++k) {
        const int f = tid + 256 * k;
        float4 w4 = w4p[f];
        float4 b4 = b4p[f];
        float4 xn;
        xn.x = (v[k].x - mu) * rs * w4.x + b4.x;
        xn.y = (v[k].y - mu) * rs * w4.y + b4.y;
        xn.z = (v[k].z - mu) * rs * w4.z + b4.z;
        xn.w = (v[k].w - mu) * rs * w4.w + b4.w;
        float4 wv = dw4[f & 15];
        dot[k] += xn.x * wv.x + xn.y * wv.y + xn.z * wv.z + xn.w * wv.w;
    }

#pragma unroll
    for (int m = 1; m <= 8; m <<= 1) {
#pragma unroll
        for (int k = 0; k < 4; ++k) dot[k] += __shfl_xor(dot[k], m);
    }

    if (tid == 0) { Mst[bt] = mu * rs; Rst[bt] = rs; }

    if ((tid & 15) == 0) {
        const int m = tid >> 4;
        const float db = dt_b[0];
        const int b = bt >> 9;
        const int t = bt & (T_SZ - 1);
#pragma unroll
        for (int k = 0; k < 4; ++k) {
            const int r = m + 16 * k;
            const float z = dot[k] + db;
            const float dt = (z > 20.f) ? z : log1pf(expf(z));
            const float A = -expf(log_A[r]);
            decay_t[((size_t)(b * D_SZ + r)) * T_SZ + t] = expf(dt * A);
        }
    }
}

// Pass A: local chunk scans, contiguous streaming. Block = (b, chunk k,
// rc-window p). Thread owns a float2 at rc = p*RCW + tid*2 (single row r).
// Streams CL slices of x in natural layout, writes only the chunk tail.
__global__ __launch_bounds__(256) void pass_tails(
    const float* __restrict__ x,
    const float* __restrict__ Mst, const float* __restrict__ Rst,
    const float* __restrict__ decay_t,
    const float* __restrict__ ln_w, const float* __restrict__ ln_b,
    float* __restrict__ tails)
{
    const int bid = blockIdx.x;           // b*NK*NPW + k*NPW + p
    const int p = bid & (NPW - 1);
    const int k = (bid >> 3) & (NK - 1);
    const int b = bid >> 8;
    const int tid = threadIdx.x;
    const int rc = p * RCW + tid * 2;
    const int r  = rc >> 6;

    const float2 w2 = *reinterpret_cast<const float2*>(ln_w + rc);
    const float2 b2 = *reinterpret_cast<const float2*>(ln_b + rc);
    const float* dp = decay_t + ((size_t)(b * D_SZ + r)) * T_SZ + k * CL;
    const float* Mp = Mst + b * T_SZ + k * CL;
    const float* Rp = Rst + b * T_SZ + k * CL;

    float2 S = make_float2(0.f, 0.f);
#pragma unroll
    for (int i = 0; i < CL; ++i) {
        const float2 xv = *reinterpret_cast<const float2*>(
            x + ((size_t)(b * T_SZ + k * CL + i)) * ELEMS + rc);
        const float d = dp[i], M = Mp[i], R = Rp[i];
        const float xnx = fmaf(fmaf(xv.x, R, -M), w2.x, b2.x);
        const float xny = fmaf(fmaf(xv.y, R, -M), w2.y, b2.y);
        S.x = fmaf(S.x, d, xnx);
        S.y = fmaf(S.y, d, xny);
    }
    *reinterpret_cast<float2*>(tails + ((size_t)(b * NK + k)) * ELEMS + rc) = S;
}

// Pass B: fold tails into per-chunk carry-ins. 16 blocks x 256 threads;
// thread owns float2 at rc. Cin[k] = fold_{j<k} (C <- tail_j + P_j*C).
__global__ __launch_bounds__(256) void pass_fold(
    const float* __restrict__ decay_t, const float* __restrict__ tails,
    float* __restrict__ cin)
{
    const int bid = blockIdx.x;           // b*NPW + p
    const int p = bid & (NPW - 1);
    const int b = bid >> 3;
    const int tid = threadIdx.x;
    const int rc = p * RCW + tid * 2;
    const int r  = rc >> 6;

    const float* drow = decay_t + ((size_t)(b * D_SZ + r)) * T_SZ;
    float2 C = make_float2(0.f, 0.f);
#pragma unroll 4
    for (int k = 0; k < NK; ++k) {
        *reinterpret_cast<float2*>(cin + ((size_t)(b * NK + k)) * ELEMS + rc) = C;
        float P = 1.f;
#pragma unroll
        for (int i = 0; i < CL; ++i) P *= drow[k * CL + i];
        const float2 t2 = *reinterpret_cast<const float2*>(
            tails + ((size_t)(b * NK + k)) * ELEMS + rc);
        C.x = fmaf(P, C.x, t2.x);
        C.y = fmaf(P, C.y, t2.y);
    }
}

// Pass C: recompute local scan (x re-read is L3-hot), apply carry, write out
// in natural contiguous layout.
__global__ __launch_bounds__(256) void pass_apply(
    const float* __restrict__ x,
    const float* __restrict__ Mst, const float* __restrict__ Rst,
    const float* __restrict__ decay_t,
    const float* __restrict__ ln_w, const float* __restrict__ ln_b,
    const float* __restrict__ cin, float* __restrict__ out)
{
    const int bid = blockIdx.x;
    const int p = bid & (NPW - 1);
    const int k = (bid >> 3) & (NK - 1);
    const int b = bid >> 8;
    const int tid = threadIdx.x;
    const int rc = p * RCW + tid * 2;
    const int r  = rc >> 6;

    const float2 w2 = *reinterpret_cast<const float2*>(ln_w + rc);
    const float2 b2 = *reinterpret_cast<const float2*>(ln_b + rc);
    const float* dp = decay_t + ((size_t)(b * D_SZ + r)) * T_SZ + k * CL;
    const float* Mp = Mst + b * T_SZ + k * CL;
    const float* Rp = Rst + b * T_SZ + k * CL;
    const float2 C2 = *reinterpret_cast<const float2*>(
        cin + ((size_t)(b * NK + k)) * ELEMS + rc);

    float2 S = make_float2(0.f, 0.f);
    float cp = 1.f;
#pragma unroll
    for (int i = 0; i < CL; ++i) {
        const size_t off = ((size_t)(b * T_SZ + k * CL + i)) * ELEMS + rc;
        const float2 xv = *reinterpret_cast<const float2*>(x + off);
        const float d = dp[i], M = Mp[i], R = Rp[i];
        const float xnx = fmaf(fmaf(xv.x, R, -M), w2.x, b2.x);
        const float xny = fmaf(fmaf(xv.y, R, -M), w2.y, b2.y);
        S.x = fmaf(S.x, d, xnx);
        S.y = fmaf(S.y, d, xny);
        cp *= d;
        float2 o;
        o.x = fmaf(cp, C2.x, S.x);
        o.y = fmaf(cp, C2.y, S.y);
        *reinterpret_cast<float2*>(out + off) = o;
    }
}

// Fallback (round-6 path) if ws is too small for tails/cin.
__global__ __launch_bounds__(512, 4) void scan_fused_kernel(
    const float* __restrict__ x,
    const float* __restrict__ Mst, const float* __restrict__ Rst,
    const float* __restrict__ decay_t,
    const float* __restrict__ ln_w, const float* __restrict__ ln_b,
    float* __restrict__ out)
{
    const int tid = threadIdx.x;
    const int col = tid & (NCOL - 1);
    const int k   = tid >> 4;
    const int row = blockIdx.x >> 2;
    const int cq  = blockIdx.x & 3;
    const int b = row >> 6;
    const int r = row & 63;
    const int c = cq * NCOL + col;
    const int t0 = k * CLEN;

    float4 dv[4], Mv[4], Rv[4];
    const float4* dp = reinterpret_cast<const float4*>(decay_t + (size_t)row * T_SZ + t0);
    const float4* Mp = reinterpret_cast<const float4*>(Mst + b * T_SZ + t0);
    const float4* Rp = reinterpret_cast<const float4*>(Rst + b * T_SZ + t0);
#pragma unroll
    for (int q = 0; q < 4; ++q) { dv[q] = dp[q]; Mv[q] = Mp[q]; Rv[q] = Rp[q]; }
    const float* df = reinterpret_cast<const float*>(dv);
    const float* Mf = reinterpret_cast<const float*>(Mv);
    const float* Rf = reinterpret_cast<const float*>(Rv);

    const float wr = ln_w[r * D_SZ + c];
    const float br = ln_b[r * D_SZ + c];
    const float* xp = x + ((size_t)(b * T_SZ + t0) * D_SZ + r) * D_SZ + c;

    float v[CLEN];
    float S = 0.f;
#pragma unroll
    for (int i = 0; i < CLEN; ++i) {
        const float xv = xp[(size_t)i * ELEMS];
        const float xn = fmaf(fmaf(xv, Rf[i], -Mf[i]), wr, br);
        S = fmaf(S, df[i], xn);
        v[i] = S;
    }

    float P = 1.f;
#pragma unroll
    for (int i = 0; i < CLEN; ++i) P *= df[i];

    __shared__ float sS[NCH][NCOL];
    __shared__ float sP[NCH];
    sS[k][col] = S;
    if (col == 0) sP[k] = P;
    __syncthreads();

    float Cin = 0.f;
    for (int j = 0; j < k; ++j)
        Cin = fmaf(sP[j], Cin, sS[j][col]);

    float* op = out + ((size_t)(b * T_SZ + t0) * D_SZ + r) * D_SZ + c;
    float rp = 1.f;
#pragma unroll
    for (int i = 0; i < CLEN; ++i) {
        rp *= df[i];
        op[(size_t)i * ELEMS] = fmaf(rp, Cin, v[i]);
    }
}

extern "C" void kernel_launch(void* const* d_in, const int* in_sizes, int n_in,
                              void* d_out, int out_size, void* d_ws, size_t ws_size,
                              hipStream_t stream) {
    const float* x     = (const float*)d_in[0];
    const float* log_A = (const float*)d_in[1];
    const float* dt_w  = (const float*)d_in[2];
    const float* dt_b  = (const float*)d_in[3];
    const float* ln_w  = (const float*)d_in[4];
    const float* ln_b  = (const float*)d_in[5];
    float* out     = (float*)d_out;
    float* decay_t = (float*)((char*)d_ws + DECAY_OFF);
    float* Mst     = (float*)((char*)d_ws + M_OFF);
    float* Rst     = (float*)((char*)d_ws + R_OFF);

    ln_dt_kernel<<<B_SZ * T_SZ, 256, 0, stream>>>(
        x, log_A, dt_w, dt_b, ln_w, ln_b, decay_t, Mst, Rst);

    if (ws_size >= WS_NEEDED) {
        float* tails = (float*)((char*)d_ws + TAILS_OFF);
        float* cinb  = (float*)((char*)d_ws + CIN_OFF);
        pass_tails<<<B_SZ * NK * NPW, 256, 0, stream>>>(
            x, Mst, Rst, decay_t, ln_w, ln_b, tails);
        pass_fold<<<B_SZ * NPW, 256, 0, stream>>>(decay_t, tails, cinb);
        pass_apply<<<B_SZ * NK * NPW, 256, 0, stream>>>(
            x, Mst, Rst, decay_t, ln_w, ln_b, cinb, out);
    } else {
        scan_fused_kernel<<<B_SZ * D_SZ * 4, 512, 0, stream>>>(
            x, Mst, Rst, decay_t, ln_w, ln_b, out);
    }
}